// Round 2
// baseline (524.867 us; speedup 1.0000x reference)
//
#include <hip/hip_runtime.h>
#include <hip/hip_bf16.h>
#include <hip/hip_fp16.h>

typedef float f32x4 __attribute__((ext_vector_type(4)));
typedef __bf16 bf16x8 __attribute__((ext_vector_type(8)));
typedef short s16x8 __attribute__((ext_vector_type(8)));
typedef unsigned short u16;

#define HWSZ 16384
#define NPIX 131072

// ws byte offsets (total ~43.1 MB — unchanged from round 1)
#define XT_OFF    0u          // float[NPIX*64]  x transposed to NHWC
#define OFFS_OFF  33554432u   // float[NPIX*18]  offset-conv output, [pix][18]
#define WB_OFF    42991616u   // u16[64*576]     deform_w as bf16, [o][k2*64+c]
#define OFFR_OFF  43065344u   // float[576*18]   offset_w reordered [k2*64+c][18]
#define STATS_OFF 43106816u   // float[256]: sums[64], sumsq[64], scale[64], shift[64]

// ---- prep: reorder/convert weights, zero BN stats ----
__global__ void kprep(const float* __restrict__ dw, const float* __restrict__ ow,
                      u16* __restrict__ Wb, float* __restrict__ offr,
                      float* __restrict__ stats) {
  int t = blockIdx.x * 256 + threadIdx.x;
  if (t < 256) stats[t] = 0.f;
  if (t < 36864) {                      // deform_w (64,64,3,3) -> Wb[o][k2*64+c] bf16
    int o = t / 576, r = t % 576;
    int c = r / 9, k2 = r % 9;
    __hip_bfloat16 h = __float2bfloat16(dw[t]);
    Wb[o * 576 + k2 * 64 + c] = __builtin_bit_cast(u16, h);
  } else if (t < 47232) {               // offset_w (18,64,3,3) -> offr[k2*64+c][18]
    int t2 = t - 36864;
    int oc = t2 / 576, r = t2 % 576;
    int c = r / 9, k2 = r % 9;
    offr[(k2 * 64 + c) * 18 + oc] = ow[t2];
  }
}

// ---- NCHW -> NHWC transpose of x ----
__global__ void ktrans(const float* __restrict__ x, float* __restrict__ xt) {
  __shared__ float tile[64][65];
  int blk = blockIdx.x;
  int b = blk >> 8, hwT = (blk & 255) * 64;
  int tx = threadIdx.x & 63, ty = threadIdx.x >> 6;
  const float* xp = x + (size_t)b * 64 * HWSZ;
#pragma unroll
  for (int r = 0; r < 16; ++r) {
    int c = r * 4 + ty;
    tile[c][tx] = xp[c * HWSZ + hwT + tx];
  }
  __syncthreads();
  float* xo = xt + ((size_t)b * HWSZ + hwT) * 64;
#pragma unroll
  for (int r = 0; r < 16; ++r) {
    int hwl = r * 4 + ty;
    xo[hwl * 64 + tx] = tile[tx][hwl];
  }
}

// ---- offset conv: 3x3, 64->18 ch, fp32, thread per pixel ----
__global__ void koffc(const float* __restrict__ xt, const float* __restrict__ offr,
                      const float* __restrict__ offb, float* __restrict__ offs) {
  int pix = blockIdx.x * 256 + threadIdx.x;
  int b = pix >> 14, hw = pix & 16383;
  int h = hw >> 7, w = hw & 127;
  float acc[18];
#pragma unroll
  for (int oc = 0; oc < 18; ++oc) acc[oc] = offb[oc];
#pragma unroll
  for (int k2 = 0; k2 < 9; ++k2) {
    int y = h - 1 + k2 / 3, x = w - 1 + k2 % 3;
    if ((unsigned)y < 128u && (unsigned)x < 128u) {
      const float* px = xt + (((b << 7) + y << 7) + x) * 64;
      const float* wr = offr + k2 * 64 * 18;
      for (int c = 0; c < 64; c += 4) {   // rolled: 16 iters x 72 FMA
        f32x4 xv = *(const f32x4*)(px + c);
#pragma unroll
        for (int j = 0; j < 4; ++j)
#pragma unroll
          for (int oc = 0; oc < 18; ++oc)
            acc[oc] = fmaf(wr[(c + j) * 18 + oc], xv[j], acc[oc]);
      }
    }
  }
  float* op = offs + (size_t)pix * 18;
#pragma unroll
  for (int oc = 0; oc < 18; ++oc) op[oc] = acc[oc];
}

// ---- deformable conv: meta precompute (LDS) + bilinear sample (LDS bf16) + MFMA ----
// block: 256 thr = 4 waves; tile = 64 o x 32 pixels; K = 576 (k2*64+c)
// LDS: S 36864 + meta 3456 = 40320 B -> 4 blocks/CU
__global__ __launch_bounds__(256, 4) void kdeform(
    const float* __restrict__ xt, const float* __restrict__ offs,
    const u16* __restrict__ Wb, const float* __restrict__ db,
    float* __restrict__ y, float* __restrict__ stats) {
  __shared__ u16 S[32 * 576];          // XOR-swizzled: u16idx ^= (row&7)<<3
  __shared__ int  mO[288];             // o00 | dxstep<<24 | dystep<<25
  __shared__ unsigned mWy[288];        // f16x2 {ay0, ay1} (validity folded in)
  __shared__ unsigned mWx[288];        // f16x2 {ax0, ax1}
  int tid = threadIdx.x;
  int lane = tid & 63, wid = tid >> 6;
  int base = blockIdx.x * 32;
  int b = base >> 14;

  // ---- phase 0: per-(pixel,tap) meta, one task per thread (288 tasks) ----
  for (int t = tid; t < 288; t += 256) {
    int tp = t / 9, k2 = t - tp * 9;
    int pix = base + tp;
    int hw = pix & 16383;
    int h = hw >> 7, w = hw & 127;
    float dy = offs[(size_t)pix * 18 + 2 * k2];
    float dx = offs[(size_t)pix * 18 + 2 * k2 + 1];
    float sy = (float)(h - 1 + k2 / 3) + dy;
    float sx = (float)(w - 1 + k2 % 3) + dx;
    float fy = floorf(sy), fx = floorf(sx);
    int y0 = (int)fy, x0 = (int)fx;
    float wy1 = sy - fy, wx1 = sx - fx;
    float wy0 = 1.f - wy1, wx0 = 1.f - wx1;
    float ay0 = ((unsigned)y0 < 128u) ? wy0 : 0.f;
    float ay1 = ((unsigned)(y0 + 1) < 128u) ? wy1 : 0.f;
    float ax0 = ((unsigned)x0 < 128u) ? wx0 : 0.f;
    float ax1 = ((unsigned)(x0 + 1) < 128u) ? wx1 : 0.f;
    int y0c = min(max(y0, 0), 127), x0c = min(max(x0, 0), 127);
    int y1c = min(max(y0 + 1, 0), 127), x1c = min(max(x0 + 1, 0), 127);
    int dys = y1c - y0c, dxs = x1c - x0c;
    mO[t] = ((b << 14) + y0c * 128 + x0c) | (dxs << 24) | (dys << 25);
    mWy[t] = __builtin_bit_cast(unsigned, __floats2half2_rn(ay0, ay1));
    mWx[t] = __builtin_bit_cast(unsigned, __floats2half2_rn(ax0, ax1));
  }
  __syncthreads();

  // ---- phase 1: sampling — wave wid handles pixels wid*8 .. wid*8+7; lane=channel ----
  for (int i = 0; i < 8; ++i) {
    int p = wid * 8 + i;
#pragma unroll
    for (int k2 = 0; k2 < 9; ++k2) {
      int t = p * 9 + k2;
      int mo = __builtin_amdgcn_readfirstlane(mO[t]);
      unsigned wyp = mWy[t], wxp = mWx[t];
      int o00 = mo & 0xFFFFFF;
      int dxs = (mo >> 24) & 1, dys = (mo >> 25) & 1;
      const float* p00 = xt + ((size_t)o00 << 6);
      float v00 = p00[lane];
      float v01 = p00[(dxs << 6) + lane];
      float v10 = p00[(dys << 13) + lane];
      float v11 = p00[(dys << 13) + (dxs << 6) + lane];
      __half2 hy = __builtin_bit_cast(__half2, wyp);
      __half2 hx = __builtin_bit_cast(__half2, wxp);
      float ay0 = __low2float(hy), ay1 = __high2float(hy);
      float ax0 = __low2float(hx), ax1 = __high2float(hx);
      float m0 = fmaf(ax1, v01, ax0 * v00);
      float m1 = fmaf(ax1, v11, ax0 * v10);
      float s = fmaf(ay1, m1, ay0 * m0);
      __hip_bfloat16 hb = __float2bfloat16(s);
      int idx = (p * 576 + k2 * 64 + lane) ^ ((p & 7) << 3);
      S[idx] = __builtin_bit_cast(u16, hb);
    }
  }

  // A fragments: W rows for this wave's 16 output channels, K=576 in 18 steps
  bf16x8 af[18];
  const u16* wrow = Wb + (wid * 16 + (lane & 15)) * 576 + (lane >> 4) * 8;
#pragma unroll
  for (int kc = 0; kc < 18; ++kc)
    af[kc] = __builtin_bit_cast(bf16x8, *(const s16x8*)(wrow + kc * 32));

  __syncthreads();

  f32x4 zero = {0.f, 0.f, 0.f, 0.f};
  f32x4 acc[2] = {zero, zero};
#pragma unroll
  for (int kc = 0; kc < 18; ++kc) {
#pragma unroll
    for (int nf = 0; nf < 2; ++nf) {
      int row = nf * 16 + (lane & 15);
      int idx = (row * 576 + kc * 32 + (lane >> 4) * 8) ^ ((row & 7) << 3);
      bf16x8 bfr = __builtin_bit_cast(bf16x8, *(const s16x8*)&S[idx]);
      acc[nf] = __builtin_amdgcn_mfma_f32_16x16x32_bf16(af[kc], bfr, acc[nf], 0, 0, 0);
    }
  }

  // epilogue: write y (NCHW) + per-channel partial sums
  int obase = wid * 16 + (lane >> 4) * 4;
  float s1[4] = {0, 0, 0, 0}, s2[4] = {0, 0, 0, 0};
#pragma unroll
  for (int nf = 0; nf < 2; ++nf) {
    int pix = base + nf * 16 + (lane & 15);
    int hw = pix & 16383;
    float* yp = y + (size_t)b * (64 * HWSZ) + hw;
#pragma unroll
    for (int r = 0; r < 4; ++r) {
      int o = obase + r;
      float v = acc[nf][r] + db[o];
      yp[(size_t)o * HWSZ] = v;
      s1[r] += v;
      s2[r] += v * v;
    }
  }
#pragma unroll
  for (int m = 1; m < 16; m <<= 1) {
#pragma unroll
    for (int r = 0; r < 4; ++r) {
      s1[r] += __shfl_xor(s1[r], m, 64);
      s2[r] += __shfl_xor(s2[r], m, 64);
    }
  }
  if ((lane & 15) == 0) {
#pragma unroll
    for (int r = 0; r < 4; ++r) {
      atomicAdd(&stats[obase + r], s1[r]);
      atomicAdd(&stats[64 + obase + r], s2[r]);
    }
  }
}

// ---- BN finalize: scale/shift per channel ----
__global__ void kbn(const float* __restrict__ gamma, const float* __restrict__ beta,
                    float* __restrict__ stats) {
  int o = threadIdx.x;
  if (o < 64) {
    float m = stats[o] * (1.f / 131072.f);
    float v = stats[64 + o] * (1.f / 131072.f) - m * m;
    float sc = gamma[o] * rsqrtf(v + 1e-5f);
    stats[128 + o] = sc;
    stats[192 + o] = beta[o] - m * sc;
  }
}

// ---- in-place scale/shift + PReLU on y (= d_out) ----
__global__ void kfinal(float* __restrict__ y, const float* __restrict__ stats,
                       const float* __restrict__ pa) {
  float a = pa[0];
  int total = NPIX * 64 / 4;
  for (int i = blockIdx.x * blockDim.x + threadIdx.x; i < total;
       i += gridDim.x * blockDim.x) {
    int o = (i >> 12) & 63;              // (i*4 >> 14) & 63
    f32x4 v = ((const f32x4*)y)[i];
    float sc = stats[128 + o], sh = stats[192 + o];
#pragma unroll
    for (int j = 0; j < 4; ++j) {
      float t = fmaf(v[j], sc, sh);
      v[j] = t >= 0.f ? t : a * t;
    }
    ((f32x4*)y)[i] = v;
  }
}

extern "C" void kernel_launch(void* const* d_in, const int* in_sizes, int n_in,
                              void* d_out, int out_size, void* d_ws, size_t ws_size,
                              hipStream_t stream) {
  const float* x  = (const float*)d_in[0];
  const float* ow = (const float*)d_in[1];
  const float* ob = (const float*)d_in[2];
  const float* dw = (const float*)d_in[3];
  const float* db = (const float*)d_in[4];
  const float* gm = (const float*)d_in[5];
  const float* bt = (const float*)d_in[6];
  const float* pa = (const float*)d_in[7];
  char* ws = (char*)d_ws;
  float* xt    = (float*)(ws + XT_OFF);
  float* offs  = (float*)(ws + OFFS_OFF);
  u16*   Wb    = (u16*)(ws + WB_OFF);
  float* offr  = (float*)(ws + OFFR_OFF);
  float* stats = (float*)(ws + STATS_OFF);
  float* y = (float*)d_out;   // use d_out as the pre-BN activation buffer

  kprep<<<185, 256, 0, stream>>>(dw, ow, Wb, offr, stats);
  ktrans<<<2048, 256, 0, stream>>>(x, xt);
  koffc<<<512, 256, 0, stream>>>(xt, offr, ob, offs);
  kdeform<<<4096, 256, 0, stream>>>(xt, offs, Wb, db, y, stats);
  kbn<<<1, 64, 0, stream>>>(gm, bt, stats);
  kfinal<<<2048, 256, 0, stream>>>(y, stats, pa);
}